// Round 8
// baseline (159.178 us; speedup 1.0000x reference)
//
#include <hip/hip_runtime.h>

static constexpr int kH = 8;      // heads
static constexpr int kD = 32;     // head dim

typedef float f4 __attribute__((ext_vector_type(4)));

__device__ __forceinline__ float dot8(const f4 a, const f4 b, const f4 c, const f4 d) {
  return a.x * b.x + a.y * b.y + a.z * b.z + a.w * b.w
       + c.x * d.x + c.y * d.y + c.z * d.z + c.w * d.w;
}

// Single fused kernel, no atomics, no workspace, no second pass over HBM.
// Edges are partitioned into contiguous chunks (one per wave). A wave OWNS
// every node whose first edge lies in its chunk; it processes each owned
// node's full edge run (possibly crossing into the next chunk; the neighbor
// wave skips those continuation edges). index is sorted, so node boundaries
// are detected by index[e] != index[e+1]; all branches are wave-uniform.
// Per edge: wave loads 1KB q + 1KB k (64 lanes x dwordx4, coalesced),
// v = exp(relu(dot)) via 3 shuffles; sub==0 lanes write out[e*8+h] and
// accumulate the node sum in a register. At node end: scale the node's
// just-written out slice (L2-hot) by 1/sum in place.
// Softmax shift-invariance + relu'd bounded scores => no seg_max needed.
__global__ void __launch_bounds__(256, 8) fused_softmax_kernel(
    const float* __restrict__ q, const float* __restrict__ k,
    const float* __restrict__ attn, const int* __restrict__ index,
    float* __restrict__ out, int nedges) {
  const int lane = threadIdx.x & 63;
  const int h = lane >> 3;
  const int sub = lane & 7;

  // per-lane attn fragment — loop-invariant
  const f4 aq = *reinterpret_cast<const f4*>(attn + h * (2 * kD) + sub * 4);
  const f4 ak = *reinterpret_cast<const f4*>(attn + h * (2 * kD) + kD + sub * 4);

  const int wave   = (blockIdx.x * blockDim.x + threadIdx.x) >> 6;
  const int nwaves = (gridDim.x * blockDim.x) >> 6;

  const int cpw = (nedges + nwaves - 1) / nwaves;  // chunk size (~49)
  const int cs = wave * cpw;
  if (cs >= nedges) return;
  const int ce = min(cs + cpw, nedges);

  // find the first node START in [cs, ce)
  int e = cs;
  if (cs > 0) {
    const int prev = index[cs - 1];
    while (e < ce && index[e] == prev) ++e;  // skip continuation of neighbor's node
    if (e >= ce) return;                     // chunk entirely inside one foreign node
  }

  const f4* qv = reinterpret_cast<const f4*>(q);
  const f4* kv = reinterpret_cast<const f4*>(k);

  int node = index[e];
  for (;;) {  // one iteration per OWNED node
    const int ns = e;
    float acc = 0.0f;
    int nxt;
    #pragma unroll 1
    do {
      // issue both 16B/lane loads + next-index load together
      const f4 q4 = __builtin_nontemporal_load(qv + (size_t)e * 64 + lane);
      const f4 k4 = __builtin_nontemporal_load(kv + (size_t)e * 64 + lane);
      nxt = (e + 1 < nedges) ? index[e + 1] : -1;

      float p = dot8(q4, aq, k4, ak);
      p += __shfl_xor(p, 1);
      p += __shfl_xor(p, 2);
      p += __shfl_xor(p, 4);
      const float v = __expf(fmaxf(p, 0.0f));

      if (sub == 0) out[(size_t)e * kH + h] = v;  // raw exp, normalized below
      acc += v;
      ++e;
    } while (nxt == node);  // wave-uniform

    // normalize the node's slice in place (just-written => L2 hit)
    const float rcp = 1.0f / acc;
    if (sub == 0) {
      #pragma unroll 1
      for (int i = ns; i < e; ++i) {
        out[(size_t)i * kH + h] *= rcp;
      }
    }

    if (nxt < 0 || e >= ce) break;  // next node start is out of our chunk
    node = nxt;
  }
}

extern "C" void kernel_launch(void* const* d_in, const int* in_sizes, int n_in,
                              void* d_out, int out_size, void* d_ws, size_t ws_size,
                              hipStream_t stream) {
  const float* q    = (const float*)d_in[0];
  const float* k    = (const float*)d_in[1];
  const float* attn = (const float*)d_in[2];
  const int* index  = (const int*)d_in[3];

  const int E = in_sizes[3];  // 400000 edges

  float* out = (float*)d_out;

  // 2048 blocks x 256 = 8192 waves; each wave owns ~49 contiguous edges' nodes.
  fused_softmax_kernel<<<2048, 256, 0, stream>>>(q, k, attn, index, out, E);
}

// Round 9
// 157.482 us; speedup vs baseline: 1.0108x; 1.0108x over previous
//
#include <hip/hip_runtime.h>

static constexpr int kH = 8;      // heads
static constexpr int kD = 32;     // head dim
static constexpr int kNN = 50000; // n_nodes (problem constant)

typedef float f4 __attribute__((ext_vector_type(4)));

__device__ __forceinline__ float dot8(const f4 a, const f4 b, const f4 c, const f4 d) {
  return a.x * b.x + a.y * b.y + a.z * b.z + a.w * b.w
       + c.x * d.x + c.y * d.y + c.z * d.z + c.w * d.w;
}

// Fused pass: v = exp(relu(q·a_q + k·a_k)); out = v; node_sum += v.
// Empirical best structure (R7, 155.8 µs): one edge per wave-iteration,
// no unroll, atomics straight to L2. All four structural variants tried
// (x2 unroll R4/R5, run-aggregated atomics R6, single-kernel fusion R8)
// regressed by 3-11 µs — this kernel runs the 819 MB q/k stream at ~93%
// of the measured pure-read ceiling (6.29 TB/s).
// Softmax shift-invariance + relu'd bounded scores => no seg_max pass needed.
__global__ void __launch_bounds__(256, 8) score_exp_kernel(
    const float* __restrict__ q, const float* __restrict__ k,
    const float* __restrict__ attn, const int* __restrict__ index,
    float* __restrict__ out, float* __restrict__ node_sum, int nedges) {
  const int lane = threadIdx.x & 63;
  const int h = lane >> 3;
  const int sub = lane & 7;

  // per-lane attn fragment — loop-invariant
  const f4 aq = *reinterpret_cast<const f4*>(attn + h * (2 * kD) + sub * 4);
  const f4 ak = *reinterpret_cast<const f4*>(attn + h * (2 * kD) + kD + sub * 4);

  const int wave   = (blockIdx.x * blockDim.x + threadIdx.x) >> 6;
  const int nwaves = (gridDim.x * blockDim.x) >> 6;

  const f4* qp = reinterpret_cast<const f4*>(q) + (size_t)wave * 64 + lane;
  const f4* kp = reinterpret_cast<const f4*>(k) + (size_t)wave * 64 + lane;
  const size_t pstep = (size_t)nwaves * 64;

  #pragma unroll 1
  for (int e = wave; e < nedges; e += nwaves, qp += pstep, kp += pstep) {
    const f4 q4 = __builtin_nontemporal_load(qp);
    const f4 k4 = __builtin_nontemporal_load(kp);

    float p = dot8(q4, aq, k4, ak);
    p += __shfl_xor(p, 1);
    p += __shfl_xor(p, 2);
    p += __shfl_xor(p, 4);

    if (sub == 0) {
      float v = __expf(fmaxf(p, 0.0f));
      out[(size_t)e * kH + h] = v;
      atomicAdd(node_sum + (size_t)index[e] * kH + h, v);
    }
  }
}

// Normalize: one thread per edge, all 8 heads vectorized (2x float4).
__global__ void __launch_bounds__(256, 8) norm_kernel(
    const int* __restrict__ index, const float* __restrict__ node_sum,
    float* __restrict__ out, int nedges) {
  int e = blockIdx.x * blockDim.x + threadIdx.x;
  if (e >= nedges) return;
  int node = index[e];
  const f4 s0 = *reinterpret_cast<const f4*>(node_sum + (size_t)node * kH);
  const f4 s1 = *reinterpret_cast<const f4*>(node_sum + (size_t)node * kH + 4);
  f4* o = reinterpret_cast<f4*>(out + (size_t)e * kH);
  f4 v0 = o[0], v1 = o[1];
  v0.x /= s0.x; v0.y /= s0.y; v0.z /= s0.z; v0.w /= s0.w;
  v1.x /= s1.x; v1.y /= s1.y; v1.z /= s1.z; v1.w /= s1.w;
  o[0] = v0; o[1] = v1;
}

extern "C" void kernel_launch(void* const* d_in, const int* in_sizes, int n_in,
                              void* d_out, int out_size, void* d_ws, size_t ws_size,
                              hipStream_t stream) {
  const float* q    = (const float*)d_in[0];
  const float* k    = (const float*)d_in[1];
  const float* attn = (const float*)d_in[2];
  const int* index  = (const int*)d_in[3];

  const int E = in_sizes[3];  // 400000 edges

  float* out      = (float*)d_out;
  float* node_sum = (float*)d_ws;

  (void)hipMemsetAsync(node_sum, 0, (size_t)kNN * kH * sizeof(float), stream);

  // 2048 blocks x 256 = 8192 waves; each wave grid-strides over ~49 edges.
  score_exp_kernel<<<2048, 256, 0, stream>>>(q, k, attn, index, out, node_sum, E);

  norm_kernel<<<(E + 255) / 256, 256, 0, stream>>>(index, node_sum, out, E);
}